// Round 8
// baseline (238.849 us; speedup 1.0000x reference)
//
#include <hip/hip_runtime.h>

// ---------------------------------------------------------------------------
// SAGE-LSTM on MI355X.
// Xpre = x@Wih^T + b precomputed per layer (hoists the input GEMM out of the
// 16-step recurrence). LSTM: gates^T = Whh.h^T with MFMA 16x16x32 bf16.
//
// R2: fp16 Xpre + gather layout + 1-step register prefetch (565 -> 117 us).
// R3: pair-split 10 waves/block (117 -> 94 us).
// R4: Whh in registers (AGPRs), 8 waves/group, h double-buffered LDS (77 us).
// R5: LDS-staged coalesced stores; v_cvt_pk_bf16_f32 packing (263 us).
// R6: out1/out2 fused into lstm epilogues (258 us).
// R7: xpre2+out1 fused into lstm1 (ping-pong XpreA/B); prep1 (245 us).
// R8: idx_lds broadcast table; lstm1/lstm2 split; vector pack (238.5 us).
//     Post-mortem: bank-conflict counter is inherent wave64 aliasing (even
//     8 words/bank) - LDS clean. VALUBusy 55% == demand; rest is barrier
//     lockstep. Regs at exactly 128 = 4 waves/SIMD cap.
// R9: - s1[n] = h1[n].Wself2 computed in lstm1 epilogue (tile already in
//       LDS; rides the coalesced-copy read). lstm2 drops 5 MB h1 read.
//     - parity s_sleep stagger: bias 2 co-resident blocks to antiphase.
// ---------------------------------------------------------------------------

#define NN   20000
#define L2E  1.4426950408889634f

typedef unsigned short u16;
typedef __attribute__((ext_vector_type(8))) short frag8;     // 8 x bf16
typedef __attribute__((ext_vector_type(4))) float facc4;     // 4 x f32 acc
typedef __attribute__((ext_vector_type(8))) _Float16 half8;  // 8 x fp16

// ---- workspace layout (bytes) ----
#define OFF_X16   0u
#define OFF_H1    5120000u
#define OFF_S1    10240000u   // fp32 [NN] = 80,000 B (ex-hN slack)
#define OFF_WIH1P 15360000u
#define OFF_WHH1P 15491072u
#define OFF_WIH2P 15622144u
#define OFF_WHH2P 15753216u
#define OFF_WS1P  15884288u
#define OFF_WN1P  15917056u
#define OFF_WS2B  15949824u
#define OFF_WN2B  15950080u
#define OFF_B1    15950336u
#define OFF_B2    15952384u
#define OFF_XPREA 15954432u   // fp16 [NN,512] = 20,480,000 B
#define OFF_XPREB 36434432u   // fp16 [NN,512] = 20,480,000 B (ends 56,914,432)

__device__ __forceinline__ u16 f2bf(float f) {
  union { float f; unsigned u; } v; v.f = f;
  unsigned r = (v.u + 0x7fffu + ((v.u >> 16) & 1u)) >> 16;  // RNE
  return (u16)r;
}
__device__ __forceinline__ float bflo(unsigned u) {
  union { unsigned u; float f; } v; v.u = u << 16; return v.f;
}
__device__ __forceinline__ float bfhi(unsigned u) {
  union { unsigned u; float f; } v; v.u = u & 0xffff0000u; return v.f;
}
__device__ __forceinline__ unsigned pk2h(float a, float b) {
  union { _Float16 h[2]; unsigned u; } v;
  v.h[0] = (_Float16)a; v.h[1] = (_Float16)b;
  return v.u;
}
// RNE f32x2 -> packed bf16x2 in one HW op (no builtin on gfx950 -> asm)
__device__ __forceinline__ unsigned pkbf(float a, float b) {
  unsigned r;
  asm("v_cvt_pk_bf16_f32 %0, %1, %2" : "=v"(r) : "v"(a), "v"(b));
  return r;
}
__device__ __forceinline__ facc4 mfma16(frag8 a, frag8 b, facc4 c) {
  return __builtin_amdgcn_mfma_f32_16x16x32_bf16(a, b, c, 0, 0, 0);
}
__device__ __forceinline__ float rcpf(float x) { return __builtin_amdgcn_rcpf(x); }
__device__ __forceinline__ float ex2(float x)  { return __builtin_amdgcn_exp2f(x); }
// x prescaled by L2E: sigmoid(x) = 1/(1+2^-xp)
__device__ __forceinline__ float sigm_ps(float xp) { return rcpf(1.f + ex2(-xp)); }
__device__ __forceinline__ float gate_scale(int row) {
  return (row >= 256 && row < 384) ? 2.f * L2E : L2E;  // g-gate rows get 2*log2e
}
__device__ __forceinline__ float dot2(unsigned a, unsigned b) {
  return bflo(a) * bflo(b) + bfhi(a) * bfhi(b);
}

// vectorized pack: frag f covers A[row][col..col+7] contiguous fp32.
// frag layout: f = (tj*4+kb)*64 + ln ; row = tj*16+(ln&15), col = kb*32+(ln>>4)*8
__device__ __forceinline__ void pack512v(frag8* dst, const float* src, int f) {
  int ln = f & 63, kb = (f >> 6) & 3, tj = f >> 8;
  int row = tj * 16 + (ln & 15);
  int col = kb * 32 + (ln >> 4) * 8;
  float s = gate_scale(row);
  const float* p = src + row * 128 + col;
  float4 v0 = *(const float4*)p;
  float4 v1 = *(const float4*)(p + 4);
  uint4 u = { pkbf(v0.x * s, v0.y * s), pkbf(v0.z * s, v0.w * s),
              pkbf(v1.x * s, v1.y * s), pkbf(v1.z * s, v1.w * s) };
  *(uint4*)&dst[f] = u;
}
__device__ __forceinline__ void pack128v(frag8* dst, const float* src, int f) {
  int ln = f & 63, kb = (f >> 6) & 3, tj = f >> 8;
  const float* p = src + (tj * 16 + (ln & 15)) * 128 + kb * 32 + (ln >> 4) * 8;
  float4 v0 = *(const float4*)p;
  float4 v1 = *(const float4*)(p + 4);
  uint4 u = { pkbf(v0.x, v0.y), pkbf(v0.z, v0.w),
              pkbf(v1.x, v1.y), pkbf(v1.z, v1.w) };
  *(uint4*)&dst[f] = u;
}

// 149 blocks x 256 = 38144 threads exact.
__global__ __launch_bounds__(256) void pack_kernel(
    const float* __restrict__ Wih1, const float* __restrict__ Whh1,
    const float* __restrict__ bih1, const float* __restrict__ bhh1,
    const float* __restrict__ Wself1, const float* __restrict__ Wneigh1,
    const float* __restrict__ Wih2, const float* __restrict__ Whh2,
    const float* __restrict__ bih2, const float* __restrict__ bhh2,
    const float* __restrict__ Wself2, const float* __restrict__ Wneigh2,
    char* __restrict__ ws)
{
  int i = blockIdx.x * 256 + threadIdx.x;
  if (i < 8192) { pack512v((frag8*)(ws + OFF_WIH1P), Wih1, i); return; }
  i -= 8192;
  if (i < 8192) { pack512v((frag8*)(ws + OFF_WHH1P), Whh1, i); return; }
  i -= 8192;
  if (i < 8192) { pack512v((frag8*)(ws + OFF_WIH2P), Wih2, i); return; }
  i -= 8192;
  if (i < 8192) { pack512v((frag8*)(ws + OFF_WHH2P), Whh2, i); return; }
  i -= 8192;
  if (i < 2048) { pack128v((frag8*)(ws + OFF_WS1P), Wself1, i); return; }
  i -= 2048;
  if (i < 2048) { pack128v((frag8*)(ws + OFF_WN1P), Wneigh1, i); return; }
  i -= 2048;
  if (i < 128) { ((u16*)(ws + OFF_WS2B))[i] = f2bf(Wself2[i]); return; }
  i -= 128;
  if (i < 128) { ((u16*)(ws + OFF_WN2B))[i] = f2bf(Wneigh2[i]); return; }
  i -= 128;
  if (i < 512) { ((float*)(ws + OFF_B1))[i] = (bih1[i] + bhh1[i]) * gate_scale(i); return; }
  i -= 512;
  if (i < 512) { ((float*)(ws + OFF_B2))[i] = (bih2[i] + bhh2[i]) * gate_scale(i); }
}

// prep1: x fp32 -> x16 bf16, and XpreA = x@Wih1^T + b1 (fp16 gather layout:
// element offset = n*512 + kt*64 + quad*16 + gate*4 + r).
__global__ __launch_bounds__(512) void prep1_kernel(
    const float* __restrict__ x,    // [NN,128] fp32
    const frag8* __restrict__ Wp,   // Wih1 packed, 8192 frags
    const float* __restrict__ bias, // [512] fp32 prescaled
    u16* __restrict__ x16,          // [NN,128] bf16 out
    u16* __restrict__ xpre)         // [NN,512] fp16 packed out
{
  __shared__ __align__(16) u16 xt[32 * 136];         // 8704 B bf16 input tile
  __shared__ __align__(16) u16 stage[32 * 520];      // 33280 B fp16 out stage
  const int tid = threadIdx.x;
  const int base = blockIdx.x * 32;
  {
    int r = tid >> 4, o = (tid & 15) * 8;            // 32 rows x 16 chunks
    const float* src = x + (size_t)(base + r) * 128 + o;
    float4 v0 = *(const float4*)(src);
    float4 v1 = *(const float4*)(src + 4);
    uint4 st = { pkbf(v0.x, v0.y), pkbf(v0.z, v0.w),
                 pkbf(v1.x, v1.y), pkbf(v1.z, v1.w) };
    *(uint4*)(xt + r * 136 + o) = st;
    *(uint4*)(x16 + (size_t)(base + r) * 128 + o) = st;
  }
  __syncthreads();
  const int lane = tid & 63, wave = tid >> 6;
  const int m = lane & 15, quad = lane >> 4;
  const int rg = wave & 1, jh = wave >> 1;
  const int r = rg * 16 + m;
  frag8 bfr[4];
#pragma unroll
  for (int kb = 0; kb < 4; ++kb)
    bfr[kb] = *(const frag8*)(xt + r * 136 + kb * 32 + quad * 8);
  u16* srow = stage + r * 520;
#pragma unroll
  for (int j = 0; j < 8; ++j) {
    const int tj = jh * 8 + j;
    float4 bv = *(const float4*)(bias + tj * 16 + quad * 4);
    facc4 acc = {bv.x, bv.y, bv.z, bv.w};
#pragma unroll
    for (int kb = 0; kb < 4; ++kb)
      acc = mfma16(Wp[(tj * 4 + kb) * 64 + lane], bfr[kb], acc);
    uint2 st = { pk2h(acc[0], acc[1]), pk2h(acc[2], acc[3]) };
    *(uint2*)(srow + (tj & 7) * 64 + quad * 16 + (tj >> 3) * 4) = st;
  }
  __syncthreads();
#pragma unroll
  for (int i = tid; i < 2048; i += 512) {            // 32 rows x 64 uint4
    int rr = i >> 6, cc = i & 63;
    ((uint4*)(xpre + (size_t)(base + rr) * 512))[cc] =
        ((const uint4*)(stage + rr * 520))[cc];
  }
}

// shared LSTM core: 16 steps, h double-buffered in h_lds, final h -> h_lds[0].
// 8 waves per 16-node group; wave g owns kt-tile g for all 4 gates; Whh
// A-fragments in registers (AGPRs). idx_lds[t][m] broadcast table.
__device__ __forceinline__ void lstm_core(
    const u16* __restrict__ Xpre, const frag8* __restrict__ Wp,
    const int* __restrict__ nbr, int node_base,
    u16 (*h_lds)[16 * 136], int (*idx_lds)[16])
{
  const int tid = threadIdx.x;
  const int lane = tid & 63, g = tid >> 6;
  const int m = lane & 15, quad = lane >> 4;

  frag8 A[4][4];
#pragma unroll
  for (int gate = 0; gate < 4; ++gate)
#pragma unroll
    for (int kb = 0; kb < 4; ++kb)
      A[gate][kb] = Wp[((gate * 8 + g) * 4 + kb) * 64 + lane];

  for (int i = tid; i < 16 * 136; i += 512) h_lds[0][i] = 0;

  // lane holds nbr[node_base + m][quad*4 + s], s=0..3
  int4 idx4 = *(const int4*)(nbr + (size_t)(node_base + m) * 16 + quad * 4);
  if (g == 0) {                                      // all waves share indices
    idx_lds[quad * 4 + 0][m] = idx4.x;
    idx_lds[quad * 4 + 1][m] = idx4.y;
    idx_lds[quad * 4 + 2][m] = idx4.z;
    idx_lds[quad * 4 + 3][m] = idx4.w;
  }

  facc4 c = {0.f, 0.f, 0.f, 0.f};

  // initial prefetch (t=0) via shfl (idx_lds not yet visible)
  int idx0 = __shfl(idx4.x, m, 64);
  const uint4* p0 = (const uint4*)(Xpre + (size_t)idx0 * 512) + g * 8 + quad * 2;
  uint4 pX0 = p0[0], pX1 = p0[1];

  // R9: bias the two co-resident blocks toward antiphase (VALU vs memory
  // phases). One-time ~2048-cycle offset for odd blocks.
  if (blockIdx.x & 1) __builtin_amdgcn_s_sleep(32);

  __syncthreads();                                   // h zeros + idx_lds ready

#pragma unroll 1
  for (int t = 0; t < 16; ++t) {
    const u16* hr = h_lds[t & 1];
    u16* hw = h_lds[(t + 1) & 1];
    int idxn = idx_lds[t < 15 ? t + 1 : 15][m];      // broadcast read (4 lanes/addr)
    const uint4* pn = (const uint4*)(Xpre + (size_t)idxn * 512) + g * 8 + quad * 2;

    frag8 bfr[4];                                    // B = full h (prev step)
#pragma unroll
    for (int kb = 0; kb < 4; ++kb)
      bfr[kb] = *(const frag8*)(hr + m * 136 + kb * 32 + quad * 8);

    union { uint4 u; half8 h; } ua, ub;
    ua.u = pX0; ub.u = pX1;
    facc4 ai = {(float)ua.h[0], (float)ua.h[1], (float)ua.h[2], (float)ua.h[3]};
    facc4 af = {(float)ua.h[4], (float)ua.h[5], (float)ua.h[6], (float)ua.h[7]};
    facc4 ag = {(float)ub.h[0], (float)ub.h[1], (float)ub.h[2], (float)ub.h[3]};
    facc4 ao = {(float)ub.h[4], (float)ub.h[5], (float)ub.h[6], (float)ub.h[7]};
    // refill prefetch: a full step of MFMA+VALU to hide under
    pX0 = pn[0]; pX1 = pn[1];

#pragma unroll
    for (int kb = 0; kb < 4; ++kb) {
      ai = mfma16(A[0][kb], bfr[kb], ai);
      af = mfma16(A[1][kb], bfr[kb], af);
      ag = mfma16(A[2][kb], bfr[kb], ag);
      ao = mfma16(A[3][kb], bfr[kb], ao);
    }

    facc4 hv;
#pragma unroll
    for (int r = 0; r < 4; ++r) {
      // fused: si*tg = (eg-1)*rcp((1+ea)(1+eg)); so*tanh(c') = (C-1)*rcp((1+eo)(1+C))
      float ea = ex2(-ai[r]);
      float eg = ex2(fminf(ag[r], 80.f));            // inf guard for numerator
      float sitg = (eg - 1.f) * rcpf((1.f + ea) * (1.f + eg));
      float sf = sigm_ps(af[r]);
      float cn = sf * c[r] + sitg;
      c[r] = cn;
      float eo = ex2(-ao[r]);
      float C  = ex2((2.f * L2E) * cn);
      hv[r] = (C - 1.f) * rcpf((1.f + eo) * (1.f + C));
    }
    uint2 hp = { pkbf(hv[0], hv[1]), pkbf(hv[2], hv[3]) };
    *(uint2*)(hw + m * 136 + g * 16 + quad * 4) = hp;
    // LDS-only drain: prefetch vmcnt loads stay in flight across barrier
    asm volatile("s_waitcnt lgkmcnt(0)" ::: "memory");
    __builtin_amdgcn_s_barrier();
  }
}

// lstm1: core + fused out1 (h1 = relu(x@Ws^T + h@Wn^T + b)) + fused
// xpre2 (XpreB = h1@Wih2^T + b2) + fused s1 (h1 . Wself2).
__global__ __launch_bounds__(512, 4) void lstm1_kernel(
    const u16* __restrict__ Xpre, const frag8* __restrict__ Wp,
    const int* __restrict__ nbr, const u16* __restrict__ xin,
    const frag8* __restrict__ Wsp, const frag8* __restrict__ Wnp,
    const float* __restrict__ bias_o,
    const frag8* __restrict__ WihX, const float* __restrict__ biasX,
    const u16* __restrict__ ws2,
    u16* __restrict__ xpreOut, u16* __restrict__ h1, float* __restrict__ s1)
{
  __shared__ __align__(16) u16 h_lds[2][16 * 136];   // 8704 B
  __shared__ int idx_lds[16][16];                    // 1024 B
  __shared__ __align__(16) u16 xstage[16 * 520];     // 16640 B
  const int tid = threadIdx.x;
  const int lane = tid & 63, g = tid >> 6;
  const int m = lane & 15, quad = lane >> 4;
  const int node_base = blockIdx.x * 16;             // 1250*16 == 20000 exact

  lstm_core(Xpre, Wp, nbr, node_base, h_lds, idx_lds);
  const u16* hf = h_lds[0];

  // ---- fused out1: wave g = j-tile g ----
  const int row = node_base + m;
  frag8 bx[4], bh[4];
#pragma unroll
  for (int kb = 0; kb < 4; ++kb) {
    bx[kb] = *(const frag8*)(xin + (size_t)row * 128 + kb * 32 + quad * 8);
    bh[kb] = *(const frag8*)(hf + m * 136 + kb * 32 + quad * 8);
  }
  float4 bv = *(const float4*)(bias_o + g * 16 + quad * 4);
  facc4 acc = {bv.x, bv.y, bv.z, bv.w};
#pragma unroll
  for (int kb = 0; kb < 4; ++kb) {
    acc = mfma16(Wsp[(g * 4 + kb) * 64 + lane], bx[kb], acc);
    acc = mfma16(Wnp[(g * 4 + kb) * 64 + lane], bh[kb], acc);
  }
  uint2 st = { pkbf(fmaxf(acc[0], 0.f), fmaxf(acc[1], 0.f)),
               pkbf(fmaxf(acc[2], 0.f), fmaxf(acc[3], 0.f)) };
  u16* stg = (u16*)h_lds[1];                         // free after final barrier
  *(uint2*)(stg + m * 136 + g * 16 + quad * 4) = st;
  __syncthreads();
  {
    // coalesced h1 write + s1 dot on the same LDS read
    const int r = tid >> 5, cc = tid & 31;           // 16 rows x 32 x 8 B
    uint2 hv2 = *(const uint2*)(stg + r * 136 + cc * 4);
    *(uint2*)(h1 + (size_t)(node_base + r) * 128 + cc * 4) = hv2;
    uint2 w = *(const uint2*)(ws2 + cc * 4);
    float p = dot2(hv2.x, w.x) + dot2(hv2.y, w.y);
#pragma unroll
    for (int s = 1; s < 32; s <<= 1) p += __shfl_xor(p, s, 64);
    if (cc == 0) s1[node_base + r] = p;
  }
  // ---- fused xpre2: XpreB = h1@Wih2^T + b2 for our 16 rows ----
  frag8 b2f[4];
#pragma unroll
  for (int kb = 0; kb < 4; ++kb)
    b2f[kb] = *(const frag8*)(stg + m * 136 + kb * 32 + quad * 8);
#pragma unroll
  for (int j = 0; j < 4; ++j) {
    const int tj = g * 4 + j;
    float4 bx2 = *(const float4*)(biasX + tj * 16 + quad * 4);
    facc4 acc2 = {bx2.x, bx2.y, bx2.z, bx2.w};
#pragma unroll
    for (int kb = 0; kb < 4; ++kb)
      acc2 = mfma16(WihX[(tj * 4 + kb) * 64 + lane], b2f[kb], acc2);
    uint2 st2 = { pk2h(acc2[0], acc2[1]), pk2h(acc2[2], acc2[3]) };
    *(uint2*)(xstage + m * 520 + (tj & 7) * 64 + quad * 16 + (tj >> 3) * 4) = st2;
  }
  __syncthreads();
#pragma unroll
  for (int i = tid; i < 1024; i += 512) {            // 16 rows x 64 uint4
    int rr = i >> 6, cc = i & 63;
    ((uint4*)(xpreOut + (size_t)(node_base + rr) * 512))[cc] =
        ((const uint4*)(xstage + rr * 520))[cc];
  }
}

// lstm2: core + fused out2 (sigmoid(s1 + h.wn2 + b)), 32 threads/node.
__global__ __launch_bounds__(512, 4) void lstm2_kernel(
    const u16* __restrict__ Xpre, const frag8* __restrict__ Wp,
    const int* __restrict__ nbr,
    const u16* __restrict__ wn2, const float* __restrict__ b2o,
    const float* __restrict__ s1, float* __restrict__ outp)
{
  __shared__ __align__(16) u16 h_lds[2][16 * 136];   // 8704 B
  __shared__ int idx_lds[16][16];                    // 1024 B
  const int tid = threadIdx.x;
  const int node_base = blockIdx.x * 16;

  lstm_core(Xpre, Wp, nbr, node_base, h_lds, idx_lds);
  const u16* hf = h_lds[0];

  const int n = tid >> 5, cc = tid & 31;
  float s1n = s1[node_base + n];                     // broadcast load (early)
  uint2 b = *(const uint2*)(hf + n * 136 + cc * 4);
  uint2 v = *(const uint2*)(wn2 + cc * 4);
  float p = dot2(b.x, v.x) + dot2(b.y, v.y);
#pragma unroll
  for (int s = 1; s < 32; s <<= 1) p += __shfl_xor(p, s, 64);
  if (cc == 0) {
    float acc = p + s1n + b2o[0];
    outp[node_base + n] = rcpf(1.f + ex2(-acc * L2E));
  }
}

extern "C" void kernel_launch(void* const* d_in, const int* in_sizes, int n_in,
                              void* d_out, int out_size, void* d_ws, size_t ws_size,
                              hipStream_t stream) {
  const float* x       = (const float*)d_in[0];
  const int*   nbr     = (const int*)d_in[1];
  const float* Wih1    = (const float*)d_in[2];
  const float* Whh1    = (const float*)d_in[3];
  const float* bih1    = (const float*)d_in[4];
  const float* bhh1    = (const float*)d_in[5];
  const float* Wself1  = (const float*)d_in[6];
  const float* Wneigh1 = (const float*)d_in[7];
  const float* bneigh1 = (const float*)d_in[8];
  const float* Wih2    = (const float*)d_in[9];
  const float* Whh2    = (const float*)d_in[10];
  const float* bih2    = (const float*)d_in[11];
  const float* bhh2    = (const float*)d_in[12];
  const float* Wself2  = (const float*)d_in[13];
  const float* Wneigh2 = (const float*)d_in[14];
  const float* bneigh2 = (const float*)d_in[15];

  char* ws = (char*)d_ws;
  u16*   x16   = (u16*)(ws + OFF_X16);
  u16*   h1    = (u16*)(ws + OFF_H1);
  float* s1    = (float*)(ws + OFF_S1);
  u16*   XpreA = (u16*)(ws + OFF_XPREA);
  u16*   XpreB = (u16*)(ws + OFF_XPREB);
  frag8* Wih1p = (frag8*)(ws + OFF_WIH1P);
  frag8* Whh1p = (frag8*)(ws + OFF_WHH1P);
  frag8* Wih2p = (frag8*)(ws + OFF_WIH2P);
  frag8* Whh2p = (frag8*)(ws + OFF_WHH2P);
  frag8* Ws1p  = (frag8*)(ws + OFF_WS1P);
  frag8* Wn1p  = (frag8*)(ws + OFF_WN1P);
  u16*   Ws2b  = (u16*)(ws + OFF_WS2B);
  u16*   Wn2b  = (u16*)(ws + OFF_WN2B);
  float* b1    = (float*)(ws + OFF_B1);
  float* b2    = (float*)(ws + OFF_B2);

  pack_kernel<<<149, 256, 0, stream>>>(Wih1, Whh1, bih1, bhh1, Wself1,
                                       Wneigh1, Wih2, Whh2, bih2, bhh2,
                                       Wself2, Wneigh2, ws);
  prep1_kernel<<<625, 512, 0, stream>>>(x, Wih1p, b1, x16, XpreA);
  // layer 1 (+ fused out1 + xpre2 -> XpreB + s1)
  lstm1_kernel<<<1250, 512, 0, stream>>>(XpreA, Whh1p, nbr, x16, Ws1p, Wn1p,
                                         bneigh1, Wih2p, b2, Ws2b,
                                         XpreB, h1, s1);
  // layer 2 (+ fused out2)
  lstm2_kernel<<<1250, 512, 0, stream>>>(XpreB, Whh2p, nbr, Wn2b, bneigh2,
                                         s1, (float*)d_out);
}

// Round 9
// 238.701 us; speedup vs baseline: 1.0006x; 1.0006x over previous
//
#include <hip/hip_runtime.h>

// ---------------------------------------------------------------------------
// SAGE-LSTM on MI355X.
// Xpre = x@Wih^T + b precomputed per layer (hoists the input GEMM out of the
// 16-step recurrence). LSTM: gates^T = Whh.h^T with MFMA 16x16x32 bf16.
//
// R2: fp16 Xpre + gather layout + 1-step register prefetch (565 -> 117 us).
// R3: pair-split 10 waves/block (117 -> 94 us).
// R4: Whh in registers (AGPRs), 8 waves/group, h double-buffered LDS (77 us).
// R5: LDS-staged coalesced stores; v_cvt_pk_bf16_f32 packing (263 us).
// R6: out1/out2 fused into lstm epilogues (258 us).
// R7: xpre2+out1 fused into lstm1 (ping-pong XpreA/B); prep1 (245 us).
// R8: idx_lds broadcast table; lstm1/lstm2 split; vector pack (238.5 us).
// R9: s1 precompute (kept, neutral); s_sleep stagger (REVERTED - blocks
//     re-converge through barrier dynamics, cost 1.6 us on lstm1).
// R10: trans-count cut 8 -> 7 per unit: fold f-gate rcp into c-update:
//     cn = [c*P + (eg-1)*Q] * rcp(P*Q), P=(1+ea)(1+eg), Q=(1+ef).
//     Exact algebra; -4 rcp instrs (~48 cy) of ~680 cy VALU per wave-step.
//     VALU issue is the saturated pipe (demand ~2720 cy/SIMD/step at 4
//     waves == measured 54% of 5400 cy wall; rest is barrier lockstep).
// ---------------------------------------------------------------------------

#define NN   20000
#define L2E  1.4426950408889634f

typedef unsigned short u16;
typedef __attribute__((ext_vector_type(8))) short frag8;     // 8 x bf16
typedef __attribute__((ext_vector_type(4))) float facc4;     // 4 x f32 acc
typedef __attribute__((ext_vector_type(8))) _Float16 half8;  // 8 x fp16

// ---- workspace layout (bytes) ----
#define OFF_X16   0u
#define OFF_H1    5120000u
#define OFF_S1    10240000u   // fp32 [NN] = 80,000 B (ex-hN slack)
#define OFF_WIH1P 15360000u
#define OFF_WHH1P 15491072u
#define OFF_WIH2P 15622144u
#define OFF_WHH2P 15753216u
#define OFF_WS1P  15884288u
#define OFF_WN1P  15917056u
#define OFF_WS2B  15949824u
#define OFF_WN2B  15950080u
#define OFF_B1    15950336u
#define OFF_B2    15952384u
#define OFF_XPREA 15954432u   // fp16 [NN,512] = 20,480,000 B
#define OFF_XPREB 36434432u   // fp16 [NN,512] = 20,480,000 B (ends 56,914,432)

__device__ __forceinline__ u16 f2bf(float f) {
  union { float f; unsigned u; } v; v.f = f;
  unsigned r = (v.u + 0x7fffu + ((v.u >> 16) & 1u)) >> 16;  // RNE
  return (u16)r;
}
__device__ __forceinline__ float bflo(unsigned u) {
  union { unsigned u; float f; } v; v.u = u << 16; return v.f;
}
__device__ __forceinline__ float bfhi(unsigned u) {
  union { unsigned u; float f; } v; v.u = u & 0xffff0000u; return v.f;
}
__device__ __forceinline__ unsigned pk2h(float a, float b) {
  union { _Float16 h[2]; unsigned u; } v;
  v.h[0] = (_Float16)a; v.h[1] = (_Float16)b;
  return v.u;
}
// RNE f32x2 -> packed bf16x2 in one HW op (no builtin on gfx950 -> asm)
__device__ __forceinline__ unsigned pkbf(float a, float b) {
  unsigned r;
  asm("v_cvt_pk_bf16_f32 %0, %1, %2" : "=v"(r) : "v"(a), "v"(b));
  return r;
}
__device__ __forceinline__ facc4 mfma16(frag8 a, frag8 b, facc4 c) {
  return __builtin_amdgcn_mfma_f32_16x16x32_bf16(a, b, c, 0, 0, 0);
}
__device__ __forceinline__ float rcpf(float x) { return __builtin_amdgcn_rcpf(x); }
__device__ __forceinline__ float ex2(float x)  { return __builtin_amdgcn_exp2f(x); }
// x prescaled by L2E: sigmoid(x) = 1/(1+2^-xp)
__device__ __forceinline__ float sigm_ps(float xp) { return rcpf(1.f + ex2(-xp)); }
__device__ __forceinline__ float gate_scale(int row) {
  return (row >= 256 && row < 384) ? 2.f * L2E : L2E;  // g-gate rows get 2*log2e
}
__device__ __forceinline__ float dot2(unsigned a, unsigned b) {
  return bflo(a) * bflo(b) + bfhi(a) * bfhi(b);
}

// vectorized pack: frag f covers A[row][col..col+7] contiguous fp32.
// frag layout: f = (tj*4+kb)*64 + ln ; row = tj*16+(ln&15), col = kb*32+(ln>>4)*8
__device__ __forceinline__ void pack512v(frag8* dst, const float* src, int f) {
  int ln = f & 63, kb = (f >> 6) & 3, tj = f >> 8;
  int row = tj * 16 + (ln & 15);
  int col = kb * 32 + (ln >> 4) * 8;
  float s = gate_scale(row);
  const float* p = src + row * 128 + col;
  float4 v0 = *(const float4*)p;
  float4 v1 = *(const float4*)(p + 4);
  uint4 u = { pkbf(v0.x * s, v0.y * s), pkbf(v0.z * s, v0.w * s),
              pkbf(v1.x * s, v1.y * s), pkbf(v1.z * s, v1.w * s) };
  *(uint4*)&dst[f] = u;
}
__device__ __forceinline__ void pack128v(frag8* dst, const float* src, int f) {
  int ln = f & 63, kb = (f >> 6) & 3, tj = f >> 8;
  const float* p = src + (tj * 16 + (ln & 15)) * 128 + kb * 32 + (ln >> 4) * 8;
  float4 v0 = *(const float4*)p;
  float4 v1 = *(const float4*)(p + 4);
  uint4 u = { pkbf(v0.x, v0.y), pkbf(v0.z, v0.w),
              pkbf(v1.x, v1.y), pkbf(v1.z, v1.w) };
  *(uint4*)&dst[f] = u;
}

// 149 blocks x 256 = 38144 threads exact.
__global__ __launch_bounds__(256) void pack_kernel(
    const float* __restrict__ Wih1, const float* __restrict__ Whh1,
    const float* __restrict__ bih1, const float* __restrict__ bhh1,
    const float* __restrict__ Wself1, const float* __restrict__ Wneigh1,
    const float* __restrict__ Wih2, const float* __restrict__ Whh2,
    const float* __restrict__ bih2, const float* __restrict__ bhh2,
    const float* __restrict__ Wself2, const float* __restrict__ Wneigh2,
    char* __restrict__ ws)
{
  int i = blockIdx.x * 256 + threadIdx.x;
  if (i < 8192) { pack512v((frag8*)(ws + OFF_WIH1P), Wih1, i); return; }
  i -= 8192;
  if (i < 8192) { pack512v((frag8*)(ws + OFF_WHH1P), Whh1, i); return; }
  i -= 8192;
  if (i < 8192) { pack512v((frag8*)(ws + OFF_WIH2P), Wih2, i); return; }
  i -= 8192;
  if (i < 8192) { pack512v((frag8*)(ws + OFF_WHH2P), Whh2, i); return; }
  i -= 8192;
  if (i < 2048) { pack128v((frag8*)(ws + OFF_WS1P), Wself1, i); return; }
  i -= 2048;
  if (i < 2048) { pack128v((frag8*)(ws + OFF_WN1P), Wneigh1, i); return; }
  i -= 2048;
  if (i < 128) { ((u16*)(ws + OFF_WS2B))[i] = f2bf(Wself2[i]); return; }
  i -= 128;
  if (i < 128) { ((u16*)(ws + OFF_WN2B))[i] = f2bf(Wneigh2[i]); return; }
  i -= 128;
  if (i < 512) { ((float*)(ws + OFF_B1))[i] = (bih1[i] + bhh1[i]) * gate_scale(i); return; }
  i -= 512;
  if (i < 512) { ((float*)(ws + OFF_B2))[i] = (bih2[i] + bhh2[i]) * gate_scale(i); }
}

// prep1: x fp32 -> x16 bf16, and XpreA = x@Wih1^T + b1 (fp16 gather layout:
// element offset = n*512 + kt*64 + quad*16 + gate*4 + r).
__global__ __launch_bounds__(512) void prep1_kernel(
    const float* __restrict__ x,    // [NN,128] fp32
    const frag8* __restrict__ Wp,   // Wih1 packed, 8192 frags
    const float* __restrict__ bias, // [512] fp32 prescaled
    u16* __restrict__ x16,          // [NN,128] bf16 out
    u16* __restrict__ xpre)         // [NN,512] fp16 packed out
{
  __shared__ __align__(16) u16 xt[32 * 136];         // 8704 B bf16 input tile
  __shared__ __align__(16) u16 stage[32 * 520];      // 33280 B fp16 out stage
  const int tid = threadIdx.x;
  const int base = blockIdx.x * 32;
  {
    int r = tid >> 4, o = (tid & 15) * 8;            // 32 rows x 16 chunks
    const float* src = x + (size_t)(base + r) * 128 + o;
    float4 v0 = *(const float4*)(src);
    float4 v1 = *(const float4*)(src + 4);
    uint4 st = { pkbf(v0.x, v0.y), pkbf(v0.z, v0.w),
                 pkbf(v1.x, v1.y), pkbf(v1.z, v1.w) };
    *(uint4*)(xt + r * 136 + o) = st;
    *(uint4*)(x16 + (size_t)(base + r) * 128 + o) = st;
  }
  __syncthreads();
  const int lane = tid & 63, wave = tid >> 6;
  const int m = lane & 15, quad = lane >> 4;
  const int rg = wave & 1, jh = wave >> 1;
  const int r = rg * 16 + m;
  frag8 bfr[4];
#pragma unroll
  for (int kb = 0; kb < 4; ++kb)
    bfr[kb] = *(const frag8*)(xt + r * 136 + kb * 32 + quad * 8);
  u16* srow = stage + r * 520;
#pragma unroll
  for (int j = 0; j < 8; ++j) {
    const int tj = jh * 8 + j;
    float4 bv = *(const float4*)(bias + tj * 16 + quad * 4);
    facc4 acc = {bv.x, bv.y, bv.z, bv.w};
#pragma unroll
    for (int kb = 0; kb < 4; ++kb)
      acc = mfma16(Wp[(tj * 4 + kb) * 64 + lane], bfr[kb], acc);
    uint2 st = { pk2h(acc[0], acc[1]), pk2h(acc[2], acc[3]) };
    *(uint2*)(srow + (tj & 7) * 64 + quad * 16 + (tj >> 3) * 4) = st;
  }
  __syncthreads();
#pragma unroll
  for (int i = tid; i < 2048; i += 512) {            // 32 rows x 64 uint4
    int rr = i >> 6, cc = i & 63;
    ((uint4*)(xpre + (size_t)(base + rr) * 512))[cc] =
        ((const uint4*)(stage + rr * 520))[cc];
  }
}

// shared LSTM core: 16 steps, h double-buffered in h_lds, final h -> h_lds[0].
// 8 waves per 16-node group; wave g owns kt-tile g for all 4 gates; Whh
// A-fragments in registers (AGPRs). idx_lds[t][m] broadcast table.
__device__ __forceinline__ void lstm_core(
    const u16* __restrict__ Xpre, const frag8* __restrict__ Wp,
    const int* __restrict__ nbr, int node_base,
    u16 (*h_lds)[16 * 136], int (*idx_lds)[16])
{
  const int tid = threadIdx.x;
  const int lane = tid & 63, g = tid >> 6;
  const int m = lane & 15, quad = lane >> 4;

  frag8 A[4][4];
#pragma unroll
  for (int gate = 0; gate < 4; ++gate)
#pragma unroll
    for (int kb = 0; kb < 4; ++kb)
      A[gate][kb] = Wp[((gate * 8 + g) * 4 + kb) * 64 + lane];

  for (int i = tid; i < 16 * 136; i += 512) h_lds[0][i] = 0;

  // lane holds nbr[node_base + m][quad*4 + s], s=0..3
  int4 idx4 = *(const int4*)(nbr + (size_t)(node_base + m) * 16 + quad * 4);
  if (g == 0) {                                      // all waves share indices
    idx_lds[quad * 4 + 0][m] = idx4.x;
    idx_lds[quad * 4 + 1][m] = idx4.y;
    idx_lds[quad * 4 + 2][m] = idx4.z;
    idx_lds[quad * 4 + 3][m] = idx4.w;
  }

  facc4 c = {0.f, 0.f, 0.f, 0.f};

  // initial prefetch (t=0) via shfl (idx_lds not yet visible)
  int idx0 = __shfl(idx4.x, m, 64);
  const uint4* p0 = (const uint4*)(Xpre + (size_t)idx0 * 512) + g * 8 + quad * 2;
  uint4 pX0 = p0[0], pX1 = p0[1];

  __syncthreads();                                   // h zeros + idx_lds ready

#pragma unroll 1
  for (int t = 0; t < 16; ++t) {
    const u16* hr = h_lds[t & 1];
    u16* hw = h_lds[(t + 1) & 1];
    int idxn = idx_lds[t < 15 ? t + 1 : 15][m];      // broadcast read (4 lanes/addr)
    const uint4* pn = (const uint4*)(Xpre + (size_t)idxn * 512) + g * 8 + quad * 2;

    frag8 bfr[4];                                    // B = full h (prev step)
#pragma unroll
    for (int kb = 0; kb < 4; ++kb)
      bfr[kb] = *(const frag8*)(hr + m * 136 + kb * 32 + quad * 8);

    union { uint4 u; half8 h; } ua, ub;
    ua.u = pX0; ub.u = pX1;
    facc4 ai = {(float)ua.h[0], (float)ua.h[1], (float)ua.h[2], (float)ua.h[3]};
    facc4 af = {(float)ua.h[4], (float)ua.h[5], (float)ua.h[6], (float)ua.h[7]};
    facc4 ag = {(float)ub.h[0], (float)ub.h[1], (float)ub.h[2], (float)ub.h[3]};
    facc4 ao = {(float)ub.h[4], (float)ub.h[5], (float)ub.h[6], (float)ub.h[7]};
    // refill prefetch: a full step of MFMA+VALU to hide under
    pX0 = pn[0]; pX1 = pn[1];

#pragma unroll
    for (int kb = 0; kb < 4; ++kb) {
      ai = mfma16(A[0][kb], bfr[kb], ai);
      af = mfma16(A[1][kb], bfr[kb], af);
      ag = mfma16(A[2][kb], bfr[kb], ag);
      ao = mfma16(A[3][kb], bfr[kb], ao);
    }

    facc4 hv;
#pragma unroll
    for (int r = 0; r < 4; ++r) {
      // R10 single-rcp c-update:
      //   cn = sf*c + si*tg = [c*P + (eg-1)*Q] * rcp(P*Q)
      //   P = (1+ea)(1+eg), Q = 1+ef   (exact algebra, one rcp)
      float ea = ex2(-ai[r]);
      float ef = ex2(-af[r]);
      float eg = ex2(fminf(ag[r], 80.f));            // overflow guard
      float G1 = 1.f + eg;
      float P  = (1.f + ea) * G1;
      float Q  = 1.f + ef;
      float num = __builtin_fmaf(c[r], P, (G1 - 2.f) * Q);
      float cn = num * rcpf(P * Q);
      c[r] = cn;
      // so*tanh(c') = (C-1)*rcp((1+eo)(1+C))
      float eo = ex2(-ao[r]);
      float C  = ex2((2.f * L2E) * cn);
      hv[r] = (C - 1.f) * rcpf((1.f + eo) * (1.f + C));
    }
    uint2 hp = { pkbf(hv[0], hv[1]), pkbf(hv[2], hv[3]) };
    *(uint2*)(hw + m * 136 + g * 16 + quad * 4) = hp;
    // LDS-only drain: prefetch vmcnt loads stay in flight across barrier
    asm volatile("s_waitcnt lgkmcnt(0)" ::: "memory");
    __builtin_amdgcn_s_barrier();
  }
}

// lstm1: core + fused out1 (h1 = relu(x@Ws^T + h@Wn^T + b)) + fused
// xpre2 (XpreB = h1@Wih2^T + b2) + fused s1 (h1 . Wself2).
__global__ __launch_bounds__(512, 4) void lstm1_kernel(
    const u16* __restrict__ Xpre, const frag8* __restrict__ Wp,
    const int* __restrict__ nbr, const u16* __restrict__ xin,
    const frag8* __restrict__ Wsp, const frag8* __restrict__ Wnp,
    const float* __restrict__ bias_o,
    const frag8* __restrict__ WihX, const float* __restrict__ biasX,
    const u16* __restrict__ ws2,
    u16* __restrict__ xpreOut, u16* __restrict__ h1, float* __restrict__ s1)
{
  __shared__ __align__(16) u16 h_lds[2][16 * 136];   // 8704 B
  __shared__ int idx_lds[16][16];                    // 1024 B
  __shared__ __align__(16) u16 xstage[16 * 520];     // 16640 B
  const int tid = threadIdx.x;
  const int lane = tid & 63, g = tid >> 6;
  const int m = lane & 15, quad = lane >> 4;
  const int node_base = blockIdx.x * 16;             // 1250*16 == 20000 exact

  lstm_core(Xpre, Wp, nbr, node_base, h_lds, idx_lds);
  const u16* hf = h_lds[0];

  // ---- fused out1: wave g = j-tile g ----
  const int row = node_base + m;
  frag8 bx[4], bh[4];
#pragma unroll
  for (int kb = 0; kb < 4; ++kb) {
    bx[kb] = *(const frag8*)(xin + (size_t)row * 128 + kb * 32 + quad * 8);
    bh[kb] = *(const frag8*)(hf + m * 136 + kb * 32 + quad * 8);
  }
  float4 bv = *(const float4*)(bias_o + g * 16 + quad * 4);
  facc4 acc = {bv.x, bv.y, bv.z, bv.w};
#pragma unroll
  for (int kb = 0; kb < 4; ++kb) {
    acc = mfma16(Wsp[(g * 4 + kb) * 64 + lane], bx[kb], acc);
    acc = mfma16(Wnp[(g * 4 + kb) * 64 + lane], bh[kb], acc);
  }
  uint2 st = { pkbf(fmaxf(acc[0], 0.f), fmaxf(acc[1], 0.f)),
               pkbf(fmaxf(acc[2], 0.f), fmaxf(acc[3], 0.f)) };
  u16* stg = (u16*)h_lds[1];                         // free after final barrier
  *(uint2*)(stg + m * 136 + g * 16 + quad * 4) = st;
  __syncthreads();
  {
    // coalesced h1 write + s1 dot on the same LDS read
    const int r = tid >> 5, cc = tid & 31;           // 16 rows x 32 x 8 B
    uint2 hv2 = *(const uint2*)(stg + r * 136 + cc * 4);
    *(uint2*)(h1 + (size_t)(node_base + r) * 128 + cc * 4) = hv2;
    uint2 w = *(const uint2*)(ws2 + cc * 4);
    float p = dot2(hv2.x, w.x) + dot2(hv2.y, w.y);
#pragma unroll
    for (int s = 1; s < 32; s <<= 1) p += __shfl_xor(p, s, 64);
    if (cc == 0) s1[node_base + r] = p;
  }
  // ---- fused xpre2: XpreB = h1@Wih2^T + b2 for our 16 rows ----
  frag8 b2f[4];
#pragma unroll
  for (int kb = 0; kb < 4; ++kb)
    b2f[kb] = *(const frag8*)(stg + m * 136 + kb * 32 + quad * 8);
#pragma unroll
  for (int j = 0; j < 4; ++j) {
    const int tj = g * 4 + j;
    float4 bx2 = *(const float4*)(biasX + tj * 16 + quad * 4);
    facc4 acc2 = {bx2.x, bx2.y, bx2.z, bx2.w};
#pragma unroll
    for (int kb = 0; kb < 4; ++kb)
      acc2 = mfma16(WihX[(tj * 4 + kb) * 64 + lane], b2f[kb], acc2);
    uint2 st2 = { pk2h(acc2[0], acc2[1]), pk2h(acc2[2], acc2[3]) };
    *(uint2*)(xstage + m * 520 + (tj & 7) * 64 + quad * 16 + (tj >> 3) * 4) = st2;
  }
  __syncthreads();
#pragma unroll
  for (int i = tid; i < 1024; i += 512) {            // 16 rows x 64 uint4
    int rr = i >> 6, cc = i & 63;
    ((uint4*)(xpreOut + (size_t)(node_base + rr) * 512))[cc] =
        ((const uint4*)(xstage + rr * 520))[cc];
  }
}

// lstm2: core + fused out2 (sigmoid(s1 + h.wn2 + b)), 32 threads/node.
__global__ __launch_bounds__(512, 4) void lstm2_kernel(
    const u16* __restrict__ Xpre, const frag8* __restrict__ Wp,
    const int* __restrict__ nbr,
    const u16* __restrict__ wn2, const float* __restrict__ b2o,
    const float* __restrict__ s1, float* __restrict__ outp)
{
  __shared__ __align__(16) u16 h_lds[2][16 * 136];   // 8704 B
  __shared__ int idx_lds[16][16];                    // 1024 B
  const int tid = threadIdx.x;
  const int node_base = blockIdx.x * 16;

  lstm_core(Xpre, Wp, nbr, node_base, h_lds, idx_lds);
  const u16* hf = h_lds[0];

  const int n = tid >> 5, cc = tid & 31;
  float s1n = s1[node_base + n];                     // broadcast load (early)
  uint2 b = *(const uint2*)(hf + n * 136 + cc * 4);
  uint2 v = *(const uint2*)(wn2 + cc * 4);
  float p = dot2(b.x, v.x) + dot2(b.y, v.y);
#pragma unroll
  for (int s = 1; s < 32; s <<= 1) p += __shfl_xor(p, s, 64);
  if (cc == 0) {
    float acc = p + s1n + b2o[0];
    outp[node_base + n] = rcpf(1.f + ex2(-acc * L2E));
  }
}

extern "C" void kernel_launch(void* const* d_in, const int* in_sizes, int n_in,
                              void* d_out, int out_size, void* d_ws, size_t ws_size,
                              hipStream_t stream) {
  const float* x       = (const float*)d_in[0];
  const int*   nbr     = (const int*)d_in[1];
  const float* Wih1    = (const float*)d_in[2];
  const float* Whh1    = (const float*)d_in[3];
  const float* bih1    = (const float*)d_in[4];
  const float* bhh1    = (const float*)d_in[5];
  const float* Wself1  = (const float*)d_in[6];
  const float* Wneigh1 = (const float*)d_in[7];
  const float* bneigh1 = (const float*)d_in[8];
  const float* Wih2    = (const float*)d_in[9];
  const float* Whh2    = (const float*)d_in[10];
  const float* bih2    = (const float*)d_in[11];
  const float* bhh2    = (const float*)d_in[12];
  const float* Wself2  = (const float*)d_in[13];
  const float* Wneigh2 = (const float*)d_in[14];
  const float* bneigh2 = (const float*)d_in[15];

  char* ws = (char*)d_ws;
  u16*   x16   = (u16*)(ws + OFF_X16);
  u16*   h1    = (u16*)(ws + OFF_H1);
  float* s1    = (float*)(ws + OFF_S1);
  u16*   XpreA = (u16*)(ws + OFF_XPREA);
  u16*   XpreB = (u16*)(ws + OFF_XPREB);
  frag8* Wih1p = (frag8*)(ws + OFF_WIH1P);
  frag8* Whh1p = (frag8*)(ws + OFF_WHH1P);
  frag8* Wih2p = (frag8*)(ws + OFF_WIH2P);
  frag8* Whh2p = (frag8*)(ws + OFF_WHH2P);
  frag8* Ws1p  = (frag8*)(ws + OFF_WS1P);
  frag8* Wn1p  = (frag8*)(ws + OFF_WN1P);
  u16*   Ws2b  = (u16*)(ws + OFF_WS2B);
  u16*   Wn2b  = (u16*)(ws + OFF_WN2B);
  float* b1    = (float*)(ws + OFF_B1);
  float* b2    = (float*)(ws + OFF_B2);

  pack_kernel<<<149, 256, 0, stream>>>(Wih1, Whh1, bih1, bhh1, Wself1,
                                       Wneigh1, Wih2, Whh2, bih2, bhh2,
                                       Wself2, Wneigh2, ws);
  prep1_kernel<<<625, 512, 0, stream>>>(x, Wih1p, b1, x16, XpreA);
  // layer 1 (+ fused out1 + xpre2 -> XpreB + s1)
  lstm1_kernel<<<1250, 512, 0, stream>>>(XpreA, Whh1p, nbr, x16, Ws1p, Wn1p,
                                         bneigh1, Wih2p, b2, Ws2b,
                                         XpreB, h1, s1);
  // layer 2 (+ fused out2)
  lstm2_kernel<<<1250, 512, 0, stream>>>(XpreB, Whh2p, nbr, Wn2b, bneigh2,
                                         s1, (float*)d_out);
}